// Round 3
// baseline (215.674 us; speedup 1.0000x reference)
//
#include <hip/hip_runtime.h>
#include <stdint.h>

#define K_DIM 8192
#define N_DIM 28672
#define NG    8    // scale-groups per wave (8 waves split K: 1024 k each)

typedef _Float16 half8 __attribute__((ext_vector_type(8)));
typedef _Float16 half2t __attribute__((ext_vector_type(2)));
typedef float f32x16 __attribute__((ext_vector_type(16)));

// ---- prep: x f32 [32][8192] -> xp f16 [K/8][32][8] in A-fragment slot order
__global__ __launch_bounds__(256) void prep_x(const float* __restrict__ x,
                                              _Float16* __restrict__ xp) {
  int idx = blockIdx.x * 256 + threadIdx.x;  // 32768 = 1024 word-rows * 32 m
  int m  = idx & 31;
  int k8 = idx >> 5;
  const float* p = x + (size_t)m * K_DIM + (size_t)k8 * 8;
  float4 xa = *(const float4*)p;
  float4 xb = *(const float4*)(p + 4);
  half2t p0 = __builtin_bit_cast(half2t, __builtin_amdgcn_cvt_pkrtz(xa.x, xb.x));
  half2t p1 = __builtin_bit_cast(half2t, __builtin_amdgcn_cvt_pkrtz(xa.y, xb.y));
  half2t p2 = __builtin_bit_cast(half2t, __builtin_amdgcn_cvt_pkrtz(xa.z, xb.z));
  half2t p3 = __builtin_bit_cast(half2t, __builtin_amdgcn_cvt_pkrtz(xa.w, xb.w));
  half8 o;
  o[0] = p0[0]; o[1] = p0[1]; o[2] = p1[0]; o[3] = p1[1];
  o[4] = p2[0]; o[5] = p2[1]; o[6] = p3[0]; o[7] = p3[1];
  *(half8*)(xp + ((size_t)k8 * 32 + m) * 8) = o;
}

// int4 word -> 8 f16 slots [n0,n4,n1,n5,n2,n6,n3,n7], value (n-8)*s (exact add)
static __device__ __forceinline__ half8 dqs(uint32_t w, half2t sh) {
  const uint32_t M4 = 0x000F000Fu, E = 0x64006400u;
  half2t off; off[0] = (_Float16)(-1032.0f); off[1] = (_Float16)(-1032.0f);
  half2t v0 = (__builtin_bit_cast(half2t, ( w        & M4) | E) + off) * sh;
  half2t v1 = (__builtin_bit_cast(half2t, ((w >> 4)  & M4) | E) + off) * sh;
  half2t v2 = (__builtin_bit_cast(half2t, ((w >> 8)  & M4) | E) + off) * sh;
  half2t v3 = (__builtin_bit_cast(half2t, ((w >> 12) & M4) | E) + off) * sh;
  half8 r;
  r[0] = v0[0]; r[1] = v0[1]; r[2] = v1[0]; r[3] = v1[1];
  r[4] = v2[0]; r[5] = v2[1]; r[6] = v3[0]; r[7] = v3[1];
  return r;
}

// gfx9 s_waitcnt imm: vm[3:0]|[15:14], exp[6:4]=7 (none), lgkm[11:8]=15 (none)
static __device__ __forceinline__ void waitcnt_vm8() { __builtin_amdgcn_s_waitcnt(0x0F78); }
static __device__ __forceinline__ void waitcnt_vm0() { __builtin_amdgcn_s_waitcnt(0x0F70); }

// One block per 32-col tile (896 blocks), 512 threads = 8 waves splitting K:
// wave w owns word-rows [w*128, w*128+128) = 8 scale-groups. No atomics, no
// LDS staging (xp is L2-hot), no barriers until the final reduce.
// Per-wave register pipeline (small enough to avoid spills at ~6 waves/SIMD):
//   scales sh[8]: fully preloaded (out of the VMEM queue)
//   Q qr[2][8]:   2-group lead (covers HBM/L3 latency)
//   A aA[8]:      single buffer; aA[i] re-issued right after MFMA i consumes
// Steady queue entering step g: [Q(g) 8 | A(g) 8 | Q(g+1) 8] -> vmcnt(8);
// vmcnt(0) only at the last step. TLP (24 waves/CU) hides the remainder.
__global__ __launch_bounds__(512, 6) void qgemm(
    const uint32_t* __restrict__ q, const float* __restrict__ scales,
    const float* __restrict__ bias, const _Float16* __restrict__ xp,
    float* __restrict__ out) {
  __shared__ float red[8][16][64];   // 32 KB cross-wave reduce buffer
  const int tid  = threadIdx.x;
  const int w    = tid >> 6;         // 0..7: K-slice owner
  const int lane = tid & 63;
  const int h    = lane >> 5;
  const int nl   = lane & 31;
  const int ct   = blockIdx.x;       // 32-col tile
  const int c0   = ct << 5;
  const int wr0  = w << 7;           // wave's first word-row

  // Preload + convert all 8 group scales (compiler-tracked loads; drained
  // before the pinned pipeline starts).
  half2t sh[8];
#pragma unroll
  for (int g = 0; g < NG; g++) {
    float s = scales[(size_t)(w * NG + g) * N_DIM + c0 + nl];
    sh[g] = __builtin_bit_cast(half2t, __builtin_amdgcn_cvt_pkrtz(s, s));
  }
  waitcnt_vm0();
  __builtin_amdgcn_sched_barrier(0);

  // 32-bit voffsets (arrays < 4 GB)
  const uint32_t qb = (uint32_t)((((uint64_t)(wr0 + h)) * N_DIM + c0 + nl) * 4);
  const uint32_t ab = (uint32_t)(((wr0 + h) * 32 + nl) * 16);

  uint32_t qr[2][8];   // Q words, 2-group lead
  float4   aA[8];      // A fragments (half8 bits), single buffer

  auto qload = [&](int g, int p) {
#pragma unroll
    for (int i = 0; i < 8; i++) {
      uint32_t vo = qb + (uint32_t)(g * 16 + 2 * i) * (uint32_t)(N_DIM * 4);
      asm volatile("global_load_dword %0, %1, %2"
                   : "=v"(qr[p][i]) : "v"(vo), "s"(q));
    }
  };
  auto aload1 = [&](int g, int i) {
    uint32_t vo = ab + (uint32_t)(g * 8192 + i * 1024);
    asm volatile("global_load_dwordx4 %0, %1, %2"
                 : "=v"(aA[i]) : "v"(vo), "s"(xp));
  };

  f32x16 acc;
#pragma unroll
  for (int j = 0; j < 16; j++) acc[j] = 0.0f;

  // prologue queue: [Q0(8), A0(8), Q1(8)]
  qload(0, 0);
#pragma unroll
  for (int i = 0; i < 8; i++) aload1(0, i);
  qload(1, 1);

#pragma unroll
  for (int g = 0; g < NG; g++) {
    // retire Q(g)+A(g); keep Q(g+1) (8 newest) in flight — never drain early
    if (g < NG - 1) waitcnt_vm8(); else waitcnt_vm0();
    __builtin_amdgcn_sched_barrier(0);   // rule #18: no consumer hoists above
    half2t s = sh[g];
#pragma unroll
    for (int i = 0; i < 8; i++) {
      acc = __builtin_amdgcn_mfma_f32_32x32x16_f16(
          __builtin_bit_cast(half8, aA[i]), dqs(qr[g & 1][i], s), acc, 0, 0, 0);
      if (g + 1 < NG) aload1(g + 1, i);  // WAR: reissue right after consume
    }
    if (g + 2 < NG) qload(g + 2, g & 1);
  }

  // cross-wave K reduction: red[w][j][lane], stride-1 -> conflict-free
#pragma unroll
  for (int j = 0; j < 16; j++) red[w][j][lane] = acc[j];
  __syncthreads();

  float b = bias[c0 + nl];
#pragma unroll
  for (int jj = 0; jj < 2; jj++) {
    int j = w * 2 + jj;
    float v = red[0][j][lane] + red[1][j][lane] + red[2][j][lane] +
              red[3][j][lane] + red[4][j][lane] + red[5][j][lane] +
              red[6][j][lane] + red[7][j][lane];
    int row = (j & 3) + ((j >> 2) << 3) + (h << 2);
    out[(size_t)row * N_DIM + c0 + nl] = v + b;
  }
}

extern "C" void kernel_launch(void* const* d_in, const int* in_sizes, int n_in,
                              void* d_out, int out_size, void* d_ws, size_t ws_size,
                              hipStream_t stream) {
  const float*    xf      = (const float*)d_in[0];
  const uint32_t* qweight = (const uint32_t*)d_in[1];
  const float*    scales  = (const float*)d_in[2];
  const float*    bias    = (const float*)d_in[3];
  float*          out     = (float*)d_out;
  _Float16*       xp      = (_Float16*)d_ws;   // 512 KB scratch

  prep_x<<<dim3(128), dim3(256), 0, stream>>>(xf, xp);
  qgemm<<<dim3(N_DIM / 32), dim3(512), 0, stream>>>(qweight, scales, bias, xp, out);
}

// Round 6
// 193.503 us; speedup vs baseline: 1.1146x; 1.1146x over previous
//
#include <hip/hip_runtime.h>
#include <stdint.h>

#define K_DIM 8192
#define N_DIM 28672
#define NG    8    // scale-groups per wave (8 waves split K: 1024 k each)

typedef _Float16 half8 __attribute__((ext_vector_type(8)));
typedef _Float16 half2t __attribute__((ext_vector_type(2)));
typedef float f32x16 __attribute__((ext_vector_type(16)));
typedef float f32x4 __attribute__((ext_vector_type(4)));
typedef uint32_t u32x2 __attribute__((ext_vector_type(2)));

// ---- prep: x f32 [32][8192] -> xp f16 [K/8][32][8] in A-fragment slot order
__global__ __launch_bounds__(256) void prep_x(const float* __restrict__ x,
                                              _Float16* __restrict__ xp) {
  int idx = blockIdx.x * 256 + threadIdx.x;  // 32768 = 1024 word-rows * 32 m
  int m  = idx & 31;
  int k8 = idx >> 5;
  const float* p = x + (size_t)m * K_DIM + (size_t)k8 * 8;
  float4 xa = *(const float4*)p;
  float4 xb = *(const float4*)(p + 4);
  half2t p0 = __builtin_bit_cast(half2t, __builtin_amdgcn_cvt_pkrtz(xa.x, xb.x));
  half2t p1 = __builtin_bit_cast(half2t, __builtin_amdgcn_cvt_pkrtz(xa.y, xb.y));
  half2t p2 = __builtin_bit_cast(half2t, __builtin_amdgcn_cvt_pkrtz(xa.z, xb.z));
  half2t p3 = __builtin_bit_cast(half2t, __builtin_amdgcn_cvt_pkrtz(xa.w, xb.w));
  half8 o;
  o[0] = p0[0]; o[1] = p0[1]; o[2] = p1[0]; o[3] = p1[1];
  o[4] = p2[0]; o[5] = p2[1]; o[6] = p3[0]; o[7] = p3[1];
  *(half8*)(xp + ((size_t)k8 * 32 + m) * 8) = o;
}

// int4 word -> 8 f16 slots [n0,n4,n1,n5,n2,n6,n3,n7], value (n-8)*s (exact add)
static __device__ __forceinline__ half8 dqs(uint32_t w, half2t sh) {
  const uint32_t M4 = 0x000F000Fu, E = 0x64006400u;
  half2t off; off[0] = (_Float16)(-1032.0f); off[1] = (_Float16)(-1032.0f);
  half2t v0 = (__builtin_bit_cast(half2t, ( w        & M4) | E) + off) * sh;
  half2t v1 = (__builtin_bit_cast(half2t, ((w >> 4)  & M4) | E) + off) * sh;
  half2t v2 = (__builtin_bit_cast(half2t, ((w >> 8)  & M4) | E) + off) * sh;
  half2t v3 = (__builtin_bit_cast(half2t, ((w >> 12) & M4) | E) + off) * sh;
  half8 r;
  r[0] = v0[0]; r[1] = v0[1]; r[2] = v1[0]; r[3] = v1[1];
  r[4] = v2[0]; r[5] = v2[1]; r[6] = v3[0]; r[7] = v3[1];
  return r;
}

static __device__ __forceinline__ half2t cvtp(float f) {
  return __builtin_bit_cast(half2t, __builtin_amdgcn_cvt_pkrtz(f, f));
}

// gfx9 s_waitcnt imm: vm[3:0]|[15:14], exp[6:4]=7 (none), lgkm[11:8]=15 (none)
static __device__ __forceinline__ void waitcnt_vm8() { __builtin_amdgcn_s_waitcnt(0x0F78); }
static __device__ __forceinline__ void waitcnt_vm0() { __builtin_amdgcn_s_waitcnt(0x0F70); }

// r3 skeleton (known-pass) + ONE delta: 64-col blocks with dwordx2 Q loads.
// Block = 64 cols x full K (448 blocks, ~2/CU). 8 waves split K: wave w owns
// word-rows [w*128, w*128+128) = 8 scale-groups. Lane (h,nl) loads Q cols
// {c0+2nl, c0+2nl+1} of row 16g+2i+h in one dwordx2 (256 B contiguous per
// 32-lane half). Word j feeds subtile j with physical col c0+2*nl+j (pure
// column relabel of the MFMA col=lane mapping; applied at store). Each A
// fragment feeds BOTH subtiles -> 2x fewer A instructions + half the A L2
// re-reads vs r3. Total VMEM instr ~460k vs r3's ~917k at identical bytes:
// this isolates the VMEM-instruction-rate theory.
// Pinned queue per step g: [Q(g)8, A(g)8, Q(g+1)8] -> vmcnt(8); A(g+1)
// reissued after consume; vmcnt(0) only at last step. No atomics; barriers
// only in the epilogue reduce.
__global__ __launch_bounds__(512, 4) void qgemm(
    const uint32_t* __restrict__ q, const float* __restrict__ scales,
    const float* __restrict__ bias, const _Float16* __restrict__ xp,
    float* __restrict__ out) {
  __shared__ float red[8][16][64];   // 32 KB cross-wave reduce buffer
  const int tid  = threadIdx.x;
  const int w    = tid >> 6;         // 0..7: K-slice owner
  const int lane = tid & 63;
  const int h    = lane >> 5;
  const int nl   = lane & 31;
  const int c0   = blockIdx.x << 6;  // 64-col tile
  const int wr0  = w << 7;           // wave's first word-row

  // Preload + convert the 16 group scales (8 groups x 2 cols per lane).
  half2t sh[8][2];
#pragma unroll
  for (int g = 0; g < NG; g++) {
#pragma unroll
    for (int j = 0; j < 2; j++) {
      float s = scales[(size_t)(w * NG + g) * N_DIM + c0 + 2 * nl + j];
      sh[g][j] = cvtp(s);
    }
  }
  waitcnt_vm0();                      // drain compiler-tracked scale loads
  __builtin_amdgcn_sched_barrier(0);

  // 32-bit voffsets (arrays < 4 GB)
  const uint32_t qb = (uint32_t)((((uint64_t)(wr0 + h)) * N_DIM + c0 + 2 * nl) * 4);
  const uint32_t ab = (uint32_t)(((wr0 + h) * 32 + nl) * 16);

  u32x2 qr[2][8];   // Q word pairs, 2-group lead
  f32x4 aA[8];      // A fragments (half8 bits), single buffer

  auto qload = [&](int g, int p) {
#pragma unroll
    for (int i = 0; i < 8; i++) {
      uint32_t vo = qb + (uint32_t)(g * 16 + 2 * i) * (uint32_t)(N_DIM * 4);
      asm volatile("global_load_dwordx2 %0, %1, %2"
                   : "=v"(qr[p][i]) : "v"(vo), "s"(q));
    }
  };
  auto aload1 = [&](int g, int i) {
    uint32_t vo = ab + (uint32_t)(g * 8192 + i * 1024);
    asm volatile("global_load_dwordx4 %0, %1, %2"
                 : "=v"(aA[i]) : "v"(vo), "s"(xp));
  };

  f32x16 acc0, acc1;
#pragma unroll
  for (int j = 0; j < 16; j++) { acc0[j] = 0.f; acc1[j] = 0.f; }

  // prologue queue: [Q0(8), A0(8), Q1(8)]
  qload(0, 0);
#pragma unroll
  for (int i = 0; i < 8; i++) aload1(0, i);
  qload(1, 1);

#pragma unroll
  for (int g = 0; g < NG; g++) {
    // retire Q(g)+A(g); keep Q(g+1) (8 newest) in flight — never drain early
    if (g < NG - 1) waitcnt_vm8(); else waitcnt_vm0();
    __builtin_amdgcn_sched_barrier(0);   // rule #18: no consumer hoists above
    half2t s0 = sh[g][0], s1 = sh[g][1];
#pragma unroll
    for (int i = 0; i < 8; i++) {
      half8 af = __builtin_bit_cast(half8, aA[i]);
      u32x2 qw = qr[g & 1][i];
      acc0 = __builtin_amdgcn_mfma_f32_32x32x16_f16(af, dqs(qw[0], s0), acc0, 0, 0, 0);
      acc1 = __builtin_amdgcn_mfma_f32_32x32x16_f16(af, dqs(qw[1], s1), acc1, 0, 0, 0);
      if (g + 1 < NG) aload1(g + 1, i);  // WAR: reissue right after consume
    }
    if (g + 2 < NG) qload(g + 2, g & 1);
  }

  // ---- epilogue: cross-wave K-reduce per subtile; physical col = c0+2*nl+j.
  float b0 = bias[c0 + 2 * nl];      // used via per-thread reload below
  (void)b0;
#pragma unroll
  for (int J = 0; J < 2; J++) {
    f32x16 accJ = (J == 0) ? acc0 : acc1;   // static select (J unrolled)
#pragma unroll
    for (int r = 0; r < 16; r++) red[w][r][lane] = accJ[r];
    __syncthreads();
#pragma unroll
    for (int s = 0; s < 2; s++) {
      int p   = tid + s * 512;
      int reg = p >> 6, ln = p & 63;
      float v = 0.f;
#pragma unroll
      for (int u = 0; u < 8; u++) v += red[u][reg][ln];
      int row = (reg & 3) + ((reg >> 2) << 3) + ((ln >> 5) << 2);
      int col = c0 + 2 * (ln & 31) + J;
      out[(size_t)row * N_DIM + col] = v + bias[col];
    }
    __syncthreads();   // red free before next subtile overwrites it
  }
}

extern "C" void kernel_launch(void* const* d_in, const int* in_sizes, int n_in,
                              void* d_out, int out_size, void* d_ws, size_t ws_size,
                              hipStream_t stream) {
  const float*    xf      = (const float*)d_in[0];
  const uint32_t* qweight = (const uint32_t*)d_in[1];
  const float*    scales  = (const float*)d_in[2];
  const float*    bias    = (const float*)d_in[3];
  float*          out     = (float*)d_out;
  _Float16*       xp      = (_Float16*)d_ws;   // 512 KB scratch

  prep_x<<<dim3(128), dim3(256), 0, stream>>>(xf, xp);
  qgemm<<<dim3(N_DIM / 64), dim3(512), 0, stream>>>(qweight, scales, bias, xp, out);
}

// Round 7
// 188.458 us; speedup vs baseline: 1.1444x; 1.0268x over previous
//
#include <hip/hip_runtime.h>
#include <stdint.h>

#define K_DIM 8192
#define N_DIM 28672
#define NG    8    // scale-groups per wave (8 waves split K: 1024 k each)

typedef _Float16 half8 __attribute__((ext_vector_type(8)));
typedef _Float16 half2t __attribute__((ext_vector_type(2)));
typedef float f32x16 __attribute__((ext_vector_type(16)));
typedef float f32x4 __attribute__((ext_vector_type(4)));
typedef uint32_t u32x4 __attribute__((ext_vector_type(4)));

// ---- prep: x f32 [32][8192] -> xp f16 [K/8][32][8] in A-fragment slot order
__global__ __launch_bounds__(256) void prep_x(const float* __restrict__ x,
                                              _Float16* __restrict__ xp) {
  int idx = blockIdx.x * 256 + threadIdx.x;  // 32768 = 1024 word-rows * 32 m
  int m  = idx & 31;
  int k8 = idx >> 5;
  const float* p = x + (size_t)m * K_DIM + (size_t)k8 * 8;
  float4 xa = *(const float4*)p;
  float4 xb = *(const float4*)(p + 4);
  half2t p0 = __builtin_bit_cast(half2t, __builtin_amdgcn_cvt_pkrtz(xa.x, xb.x));
  half2t p1 = __builtin_bit_cast(half2t, __builtin_amdgcn_cvt_pkrtz(xa.y, xb.y));
  half2t p2 = __builtin_bit_cast(half2t, __builtin_amdgcn_cvt_pkrtz(xa.z, xb.z));
  half2t p3 = __builtin_bit_cast(half2t, __builtin_amdgcn_cvt_pkrtz(xa.w, xb.w));
  half8 o;
  o[0] = p0[0]; o[1] = p0[1]; o[2] = p1[0]; o[3] = p1[1];
  o[4] = p2[0]; o[5] = p2[1]; o[6] = p3[0]; o[7] = p3[1];
  *(half8*)(xp + ((size_t)k8 * 32 + m) * 8) = o;
}

// int4 word -> 8 f16 slots [n0,n4,n1,n5,n2,n6,n3,n7], value (n-8)*s (exact add)
static __device__ __forceinline__ half8 dqs(uint32_t w, half2t sh) {
  const uint32_t M4 = 0x000F000Fu, E = 0x64006400u;
  half2t off; off[0] = (_Float16)(-1032.0f); off[1] = (_Float16)(-1032.0f);
  half2t v0 = (__builtin_bit_cast(half2t, ( w        & M4) | E) + off) * sh;
  half2t v1 = (__builtin_bit_cast(half2t, ((w >> 4)  & M4) | E) + off) * sh;
  half2t v2 = (__builtin_bit_cast(half2t, ((w >> 8)  & M4) | E) + off) * sh;
  half2t v3 = (__builtin_bit_cast(half2t, ((w >> 12) & M4) | E) + off) * sh;
  half8 r;
  r[0] = v0[0]; r[1] = v0[1]; r[2] = v1[0]; r[3] = v1[1];
  r[4] = v2[0]; r[5] = v2[1]; r[6] = v3[0]; r[7] = v3[1];
  return r;
}

static __device__ __forceinline__ half2t cvtp(float f) {
  return __builtin_bit_cast(half2t, __builtin_amdgcn_cvt_pkrtz(f, f));
}

// gfx9 s_waitcnt imm: vm[3:0]|[15:14], exp[6:4]=7 (none), lgkm[11:8]=15 (none)
static __device__ __forceinline__ void waitcnt_vm8() { __builtin_amdgcn_s_waitcnt(0x0F78); }
static __device__ __forceinline__ void waitcnt_vm0() { __builtin_amdgcn_s_waitcnt(0x0F70); }

// r6 skeleton (known-pass) + ONE delta: 128-col blocks with dwordx4 Q loads.
// Block = 128 cols x full K (224 blocks, ~1/CU). 8 waves split K: wave w owns
// word-rows [w*128, w*128+128) = 8 scale-groups. Lane (h,nl) loads Q cols
// {c0+4nl .. c0+4nl+3} of row 16g+2i+h in one dwordx4 (1 KB contiguous per
// 32-lane half). Word j feeds subtile j with physical col c0+4*nl+j (pure
// column relabel of the MFMA col=lane mapping; applied at store — exactly
// the relabel r6 validated at 2 cols). Each A fragment feeds all FOUR
// subtiles -> 4x fewer A instructions + 1/4 the A L2 re-reads vs r3.
// Total VMEM instr ~229k vs r6's ~459k at identical bytes: factor-2 probe
// of the confirmed VMEM-instruction-rate bottleneck.
// Pinned queue per step g: [Q(g)8, A(g)8, Q(g+1)8] -> vmcnt(8); A(g+1)
// reissued after consume; vmcnt(0) only at last step. No atomics; barriers
// only in the epilogue reduce. Scales preloaded to registers (f32x4
// coalesced, no LDS staging — r4/r5's extra machinery dropped wholesale).
__global__ __launch_bounds__(512, 2) void qgemm(
    const uint32_t* __restrict__ q, const float* __restrict__ scales,
    const float* __restrict__ bias, const _Float16* __restrict__ xp,
    float* __restrict__ out) {
  __shared__ float red[8][16][64];   // 32 KB cross-wave reduce buffer
  const int tid  = threadIdx.x;
  const int w    = tid >> 6;         // 0..7: K-slice owner
  const int lane = tid & 63;
  const int h    = lane >> 5;
  const int nl   = lane & 31;
  const int c0   = blockIdx.x << 7;  // 128-col tile
  const int wr0  = w << 7;           // wave's first word-row

  // Preload + convert the 32 group scales (8 groups x 4 cols per lane),
  // one coalesced f32x4 per group.
  half2t sh[8][4];
#pragma unroll
  for (int g = 0; g < NG; g++) {
    f32x4 sv = *(const f32x4*)&scales[(size_t)(w * NG + g) * N_DIM + c0 + 4 * nl];
    sh[g][0] = cvtp(sv[0]); sh[g][1] = cvtp(sv[1]);
    sh[g][2] = cvtp(sv[2]); sh[g][3] = cvtp(sv[3]);
  }
  waitcnt_vm0();                      // drain compiler-tracked scale loads
  __builtin_amdgcn_sched_barrier(0);

  // 32-bit voffsets (arrays < 4 GB)
  const uint32_t qb = (uint32_t)((((uint64_t)(wr0 + h)) * N_DIM + c0 + 4 * nl) * 4);
  const uint32_t ab = (uint32_t)(((wr0 + h) * 32 + nl) * 16);

  u32x4 qr[2][8];   // Q word quads, 2-group lead
  f32x4 aA[8];      // A fragments (half8 bits), single buffer

  auto qload = [&](int g, int p) {
#pragma unroll
    for (int i = 0; i < 8; i++) {
      uint32_t vo = qb + (uint32_t)(g * 16 + 2 * i) * (uint32_t)(N_DIM * 4);
      asm volatile("global_load_dwordx4 %0, %1, %2"
                   : "=v"(qr[p][i]) : "v"(vo), "s"(q));
    }
  };
  auto aload1 = [&](int g, int i) {
    uint32_t vo = ab + (uint32_t)(g * 8192 + i * 1024);
    asm volatile("global_load_dwordx4 %0, %1, %2"
                 : "=v"(aA[i]) : "v"(vo), "s"(xp));
  };

  f32x16 acc0, acc1, acc2, acc3;
#pragma unroll
  for (int j = 0; j < 16; j++) { acc0[j] = 0.f; acc1[j] = 0.f; acc2[j] = 0.f; acc3[j] = 0.f; }

  // prologue queue: [Q0(8), A0(8), Q1(8)]
  qload(0, 0);
#pragma unroll
  for (int i = 0; i < 8; i++) aload1(0, i);
  qload(1, 1);

#pragma unroll
  for (int g = 0; g < NG; g++) {
    // retire Q(g)+A(g); keep Q(g+1) (8 newest) in flight — never drain early
    if (g < NG - 1) waitcnt_vm8(); else waitcnt_vm0();
    __builtin_amdgcn_sched_barrier(0);   // rule #18: no consumer hoists above
    half2t s0 = sh[g][0], s1 = sh[g][1], s2 = sh[g][2], s3 = sh[g][3];
#pragma unroll
    for (int i = 0; i < 8; i++) {
      half8 af = __builtin_bit_cast(half8, aA[i]);
      u32x4 qw = qr[g & 1][i];
      acc0 = __builtin_amdgcn_mfma_f32_32x32x16_f16(af, dqs(qw[0], s0), acc0, 0, 0, 0);
      acc1 = __builtin_amdgcn_mfma_f32_32x32x16_f16(af, dqs(qw[1], s1), acc1, 0, 0, 0);
      acc2 = __builtin_amdgcn_mfma_f32_32x32x16_f16(af, dqs(qw[2], s2), acc2, 0, 0, 0);
      acc3 = __builtin_amdgcn_mfma_f32_32x32x16_f16(af, dqs(qw[3], s3), acc3, 0, 0, 0);
      if (g + 1 < NG) aload1(g + 1, i);  // WAR: reissue right after consume
    }
    if (g + 2 < NG) qload(g + 2, g & 1);
  }

  // ---- epilogue: cross-wave K-reduce per subtile; physical col = c0+4*nl+J.
#pragma unroll
  for (int J = 0; J < 4; J++) {
    f32x16 accJ = (J == 0) ? acc0 : (J == 1) ? acc1 : (J == 2) ? acc2 : acc3;
#pragma unroll
    for (int r = 0; r < 16; r++) red[w][r][lane] = accJ[r];
    __syncthreads();
#pragma unroll
    for (int s = 0; s < 2; s++) {
      int p   = tid + s * 512;
      int reg = p >> 6, ln = p & 63;
      float v = 0.f;
#pragma unroll
      for (int u = 0; u < 8; u++) v += red[u][reg][ln];
      int row = (reg & 3) + ((reg >> 2) << 3) + ((ln >> 5) << 2);
      int col = c0 + 4 * (ln & 31) + J;
      out[(size_t)row * N_DIM + col] = v + bias[col];
    }
    __syncthreads();   // red free before next subtile overwrites it
  }
}

extern "C" void kernel_launch(void* const* d_in, const int* in_sizes, int n_in,
                              void* d_out, int out_size, void* d_ws, size_t ws_size,
                              hipStream_t stream) {
  const float*    xf      = (const float*)d_in[0];
  const uint32_t* qweight = (const uint32_t*)d_in[1];
  const float*    scales  = (const float*)d_in[2];
  const float*    bias    = (const float*)d_in[3];
  float*          out     = (float*)d_out;
  _Float16*       xp      = (_Float16*)d_ws;   // 512 KB scratch

  prep_x<<<dim3(128), dim3(256), 0, stream>>>(xf, xp);
  qgemm<<<dim3(N_DIM / 128), dim3(512), 0, stream>>>(qweight, scales, bias, xp, out);
}